// Round 2
// baseline (1090.951 us; speedup 1.0000x reference)
//
#include <hip/hip_runtime.h>
#include <math.h>

#define BB 128
#define PP 34125
#define OO 16
#define CC 21
#define HBINS 8192
#define HSHIFT 18
#define CAND_MAX 2048
#define VAR0f 0.1f
#define VAR1f 0.2f
#define THRESHf 0.35f

// ---------------- Phase A: best prior per truth (argmax over P), 8 blocks/row ----------------
__global__ __launch_bounds__(256) void mb_phaseA(const float* __restrict__ priors,
                                                 const float* __restrict__ targets,
                                                 unsigned long long* __restrict__ keys) {
    int b = blockIdx.y, tid = threadIdx.x;
    __shared__ float tr[OO][4];
    __shared__ unsigned long long skeys[OO];
    if (tid < OO * 5) {
        int o = tid / 5, c = tid % 5;
        float v = targets[((size_t)b * OO + o) * 5 + c];
        if (c < 4) tr[o][c] = v;
    }
    if (tid < OO) skeys[tid] = 0ull;
    __syncthreads();

    unsigned long long best[OO];
#pragma unroll
    for (int o = 0; o < OO; o++) best[o] = 0ull;

    for (int p = blockIdx.x * 256 + tid; p < PP; p += gridDim.x * 256) {
        float4 pr = ((const float4*)priors)[p];
        float bx0 = pr.x - pr.z * 0.5f, by0 = pr.y - pr.w * 0.5f;
        float bx1 = pr.x + pr.z * 0.5f, by1 = pr.y + pr.w * 0.5f;
        float area_b = (bx1 - bx0) * (by1 - by0);
#pragma unroll
        for (int o = 0; o < OO; o++) {
            float iw = fminf(tr[o][2], bx1) - fmaxf(tr[o][0], bx0);
            float ih = fminf(tr[o][3], by1) - fmaxf(tr[o][1], by0);
            iw = fmaxf(iw, 0.f); ih = fmaxf(ih, 0.f);
            float inter = iw * ih;
            float area_a = (tr[o][2] - tr[o][0]) * (tr[o][3] - tr[o][1]);
            float iou = inter / (area_a + area_b - inter);
            unsigned long long key =
                ((unsigned long long)__float_as_uint(iou) << 32) |
                (unsigned long long)(0xFFFFFFFFu - (unsigned)p);
            if (key > best[o]) best[o] = key;
        }
    }
    // wave-level butterfly reduce, then LDS atomics, then global
#pragma unroll
    for (int o = 0; o < OO; o++) {
        unsigned long long v = best[o];
        for (int off = 32; off > 0; off >>= 1) {
            unsigned long long other = __shfl_down(v, off, 64);
            if (other > v) v = other;
        }
        best[o] = v;
    }
    if ((tid & 63) == 0) {
#pragma unroll
        for (int o = 0; o < OO; o++) atomicMax(&skeys[o], best[o]);
    }
    __syncthreads();
    if (tid < OO) atomicMax(&keys[b * OO + tid], skeys[tid]);
}

// ---------------- Phase C: match + encode + smooth-L1 + CE + mined + histogram ----------------
__device__ __forceinline__ float sl1(float d) {
    float a = fabsf(d);
    return (a < 1.f) ? 0.5f * d * d : a - 0.5f;
}

__global__ __launch_bounds__(256) void mb_phaseC(const float* __restrict__ loc_data,
                                                 const float* __restrict__ conf_data,
                                                 const float* __restrict__ priors,
                                                 const float* __restrict__ targets,
                                                 const unsigned long long* __restrict__ keys,
                                                 float* __restrict__ mined,
                                                 unsigned* __restrict__ hist,
                                                 int* __restrict__ num_pos,
                                                 double* __restrict__ posCE,
                                                 double* __restrict__ loss_l_acc) {
    int b = blockIdx.y, tid = threadIdx.x;
    int wave = tid >> 6, lane = tid & 63;
    int p = blockIdx.x * 256 + tid;

    __shared__ float confs[4][64 * CC];   // 21504 B
    __shared__ float tr[OO][4];
    __shared__ float lab[OO];
    __shared__ unsigned bps[OO];
    __shared__ float redf[8];
    __shared__ int redi[4];

    if (tid < OO * 5) {
        int o = tid / 5, c = tid % 5;
        float v = targets[((size_t)b * OO + o) * 5 + c];
        if (c < 4) tr[o][c] = v; else lab[o] = v;
    }
    if (tid < OO) bps[tid] = 0xFFFFFFFFu - (unsigned)(keys[b * OO + tid] & 0xFFFFFFFFull);

    // stage this wave's 64 priors x 21 classes, fully coalesced dword loads
    int wbase = blockIdx.x * 256 + wave * 64;
    if (wbase < PP) {
        int ndw = min(64, PP - wbase) * CC;
        const float* src = conf_data + ((size_t)b * PP + wbase) * CC;
        float* dst = confs[wave];
        for (int j = lane; j < ndw; j += 64) dst[j] = src[j];
    }
    __syncthreads();

    float t_lossl = 0.f, t_posce = 0.f;
    int t_pos = 0;

    if (p < PP) {
        float4 pr = ((const float4*)priors)[p];
        float bx0 = pr.x - pr.z * 0.5f, by0 = pr.y - pr.w * 0.5f;
        float bx1 = pr.x + pr.z * 0.5f, by1 = pr.y + pr.w * 0.5f;
        float area_b = (bx1 - bx0) * (by1 - by0);
        float bto = -1.f;
        int bti = 0;
#pragma unroll
        for (int o = 0; o < OO; o++) {
            float iw = fminf(tr[o][2], bx1) - fmaxf(tr[o][0], bx0);
            float ih = fminf(tr[o][3], by1) - fmaxf(tr[o][1], by0);
            iw = fmaxf(iw, 0.f); ih = fmaxf(ih, 0.f);
            float inter = iw * ih;
            float area_a = (tr[o][2] - tr[o][0]) * (tr[o][3] - tr[o][1]);
            float iou = inter / (area_a + area_b - inter);
            if (iou > bto) { bto = iou; bti = o; }   // strict > : argmax first-index
        }
#pragma unroll
        for (int o = 0; o < OO; o++) {
            if (bps[o] == (unsigned)p) { bto = 2.0f; bti = o; }  // ascending o = last-wins
        }
        int conf_t = (bto < THRESHf) ? 0 : (int)lab[bti];
        bool pos = conf_t > 0;

        if (pos) {
            float mx0 = tr[bti][0], my0 = tr[bti][1], mx1 = tr[bti][2], my1 = tr[bti][3];
            float gcx = ((mx0 + mx1) * 0.5f - pr.x) / (VAR0f * pr.z);
            float gcy = ((my0 + my1) * 0.5f - pr.y) / (VAR0f * pr.w);
            float gw = logf((mx1 - mx0) / pr.z) / VAR1f;
            float gh = logf((my1 - my0) / pr.w) / VAR1f;
            float4 ld = ((const float4*)loc_data)[(size_t)b * PP + p];
            t_lossl = sl1(ld.x - gcx) + sl1(ld.y - gcy) + sl1(ld.z - gw) + sl1(ld.w - gh);
            t_pos = 1;
        }

        const float* cp = confs[wave] + lane * CC;   // stride-21 LDS: 2-way bank alias = free
        float m = cp[0];
#pragma unroll
        for (int c = 1; c < CC; c++) m = fmaxf(m, cp[c]);
        float s = 0.f;
#pragma unroll
        for (int c = 0; c < CC; c++) s += expf(cp[c] - m);
        float lse = m + logf(s);
        float ce = lse - cp[conf_t];
        if (pos) t_posce = ce;
        float mval = pos ? 0.f : ce;
        mined[(size_t)b * PP + p] = mval;
        atomicAdd(&hist[(size_t)b * HBINS + (__float_as_uint(mval) >> HSHIFT)], 1u);
    }

    // wave shuffle reductions
    for (int off = 32; off > 0; off >>= 1) {
        t_lossl += __shfl_down(t_lossl, off, 64);
        t_posce += __shfl_down(t_posce, off, 64);
        t_pos   += __shfl_down(t_pos, off, 64);
    }
    if (lane == 0) { redf[wave] = t_lossl; redf[4 + wave] = t_posce; redi[wave] = t_pos; }
    __syncthreads();
    if (tid == 0) {
        float ll = redf[0] + redf[1] + redf[2] + redf[3];
        float pc = redf[4] + redf[5] + redf[6] + redf[7];
        int np = redi[0] + redi[1] + redi[2] + redi[3];
        if (ll != 0.f) atomicAdd(loss_l_acc, (double)ll);
        if (pc != 0.f) atomicAdd(&posCE[b], (double)pc);
        if (np) atomicAdd(&num_pos[b], np);
    }
}

// ---------------- Phase D: histogram-select top-num_neg + exact in-bin rank-select ----------------
__global__ __launch_bounds__(256) void mb_phaseD(const float* __restrict__ mined,
                                                 const unsigned* __restrict__ hist,
                                                 const int* __restrict__ num_pos,
                                                 const double* __restrict__ posCE,
                                                 double* __restrict__ loss_c_acc) {
    int b = blockIdx.x, tid = threadIdx.x;
    int np = num_pos[b];
    int k = min(3 * np, PP - 1);
    if (k <= 0) {
        if (tid == 0) atomicAdd(loss_c_acc, posCE[b]);
        return;
    }
    const float* row = mined + (size_t)b * PP;
    const unsigned* h = hist + (size_t)b * HBINS;
    const int CH = HBINS / 256;   // 32 bins per thread

    __shared__ unsigned cs[256];
    __shared__ int sBin;
    __shared__ unsigned sAbove;
    __shared__ double sd[256];

    unsigned s = 0;
    for (int j = 0; j < CH; j++) s += h[tid * CH + j];
    cs[tid] = s;
    __syncthreads();
    if (tid == 0) {
        unsigned cum = 0;
        int t = 255;
        for (; t > 0; --t) {
            if (cum + cs[t] >= (unsigned)k) break;
            cum += cs[t];
        }
        int base = t * CH, bin = base;
        unsigned cum2 = cum;
        for (int j = CH - 1; j >= 1; --j) {
            unsigned c = h[base + j];
            if (cum2 + c >= (unsigned)k) { bin = base + j; break; }
            cum2 += c;
        }
        sBin = bin;
        sAbove = cum2;
    }
    __syncthreads();
    int bin = sBin;
    int need = k - (int)sAbove;        // 1..h[bin]
    unsigned binCount = h[bin];

    if (binCount <= CAND_MAX) {
        __shared__ float cand[CAND_MAX];
        __shared__ unsigned ccnt;
        if (tid == 0) ccnt = 0;
        __syncthreads();
        double sgt = 0.0;
        for (int p = tid; p < PP; p += 256) {
            float x = row[p];
            int bb = (int)(__float_as_uint(x) >> HSHIFT);
            if (bb > bin) sgt += (double)x;
            else if (bb == bin) { unsigned i = atomicAdd(&ccnt, 1u); cand[i] = x; }
        }
        sd[tid] = sgt;
        __syncthreads();
        for (int s2 = 128; s2 > 0; s2 >>= 1) {
            if (tid < s2) sd[tid] += sd[tid + s2];
            __syncthreads();
        }
        double sum_gt = sd[0];
        int n = (int)ccnt;
        __syncthreads();
        // exact rank-select: include candidate i iff stable-rank < need (ties sum identically)
        double st = 0.0;
        for (int i = tid; i < n; i += 256) {
            float v = cand[i];
            int r = 0;
            for (int j = 0; j < n; j++) {
                float w = cand[j];
                r += (w > v) || (w == v && j < i);
            }
            if (r < need) st += (double)v;
        }
        sd[tid] = st;
        __syncthreads();
        for (int s2 = 128; s2 > 0; s2 >>= 1) {
            if (tid < s2) sd[tid] += sd[tid + s2];
            __syncthreads();
        }
        if (tid == 0) atomicAdd(loss_c_acc, posCE[b] + sum_gt + sd[0]);
    } else {
        // fallback: known-correct 4-pass byte radix select over full 32 bits
        __shared__ unsigned rhist[256];
        __shared__ unsigned s_prefix;
        __shared__ int s_needed;
        unsigned prefix = 0;
        int needed = k;
        for (int pass = 0; pass < 4; pass++) {
            int shift = 24 - 8 * pass;
            for (int i = tid; i < 256; i += 256) rhist[i] = 0;
            __syncthreads();
            unsigned hi_mask = (pass == 0) ? 0u : (0xFFFFFFFFu << (shift + 8));
            for (int p = tid; p < PP; p += 256) {
                unsigned x = __float_as_uint(row[p]);
                if ((x & hi_mask) == (prefix & hi_mask))
                    atomicAdd(&rhist[(x >> shift) & 0xFFu], 1u);
            }
            __syncthreads();
            if (tid == 0) {
                unsigned cum = 0; int bsel = 0;
                for (int j = 255; j >= 0; j--) {
                    if (cum + rhist[j] >= (unsigned)needed) { bsel = j; break; }
                    cum += rhist[j];
                }
                s_prefix = prefix | ((unsigned)bsel << shift);
                s_needed = needed - (int)cum;
            }
            __syncthreads();
            prefix = s_prefix;
            needed = s_needed;
            __syncthreads();
        }
        float t = __uint_as_float(prefix);
        double sum_gt = 0.0;
        for (int p = tid; p < PP; p += 256) {
            float x = row[p];
            if (__float_as_uint(x) > prefix) sum_gt += (double)x;
        }
        sd[tid] = sum_gt;
        __syncthreads();
        for (int s2 = 128; s2 > 0; s2 >>= 1) {
            if (tid < s2) sd[tid] += sd[tid + s2];
            __syncthreads();
        }
        if (tid == 0)
            atomicAdd(loss_c_acc, posCE[b] + sd[0] + (double)needed * (double)t);
    }
}

// ---------------- Phase E: finalize ----------------
__global__ __launch_bounds__(128) void mb_phaseE(const int* __restrict__ num_pos,
                                                 const double* __restrict__ loss_l_acc,
                                                 const double* __restrict__ loss_c_acc,
                                                 float* __restrict__ out) {
    __shared__ int si[128];
    int tid = threadIdx.x;
    si[tid] = (tid < BB) ? num_pos[tid] : 0;
    __syncthreads();
    for (int s = 64; s > 0; s >>= 1) {
        if (tid < s) si[tid] += si[tid + s];
        __syncthreads();
    }
    if (tid == 0) {
        int n = si[0];
        double N = (n > 0) ? (double)n : (double)BB;
        out[0] = (float)(*loss_l_acc / N);
        out[1] = (float)(*loss_c_acc / N);
    }
}

extern "C" void kernel_launch(void* const* d_in, const int* in_sizes, int n_in,
                              void* d_out, int out_size, void* d_ws, size_t ws_size,
                              hipStream_t stream) {
    const float* loc_data  = (const float*)d_in[0];
    const float* conf_data = (const float*)d_in[1];
    const float* priors    = (const float*)d_in[2];
    const float* targets   = (const float*)d_in[3];

    char* ws = (char*)d_ws;
    // layout: [0..8) loss_l, [8..16) loss_c, [64..576) num_pos[B],
    //         [1024..2048) posCE[B], [2048..18432) keys[B*16] u64,
    //         [32768..32768+4MB) hist[B*8192] u32, then mined[B*P] f32
    double*             loss_l  = (double*)(ws + 0);
    double*             loss_c  = (double*)(ws + 8);
    int*                num_pos = (int*)(ws + 64);
    double*             posCE   = (double*)(ws + 1024);
    unsigned long long* keys    = (unsigned long long*)(ws + 2048);
    unsigned*           hist    = (unsigned*)(ws + 32768);
    float*              mined   = (float*)(ws + 32768 + (size_t)BB * HBINS * 4);

    hipMemsetAsync(ws, 0, 32768 + (size_t)BB * HBINS * 4, stream);

    mb_phaseA<<<dim3(8, BB), 256, 0, stream>>>(priors, targets, keys);

    dim3 gridC((PP + 255) / 256, BB);
    mb_phaseC<<<gridC, 256, 0, stream>>>(loc_data, conf_data, priors, targets, keys,
                                         mined, hist, num_pos, posCE, loss_l);

    mb_phaseD<<<BB, 256, 0, stream>>>(mined, hist, num_pos, posCE, loss_c);

    mb_phaseE<<<1, 128, 0, stream>>>(num_pos, loss_l, loss_c, (float*)d_out);
}

// Round 3
// 957.598 us; speedup vs baseline: 1.1393x; 1.1393x over previous
//
#include <hip/hip_runtime.h>
#include <math.h>

#define BB 128
#define PP 34125
#define OO 16
#define CC 21
#define HBINS 8192
#define HSHIFT 18
#define CAND_MAX 2048
#define VAR0f 0.1f
#define VAR1f 0.2f
#define THRESHf 0.35f

// ---------------- Phase A: best prior per truth (argmax over P), 8 blocks/row ----------------
__global__ __launch_bounds__(256) void mb_phaseA(const float* __restrict__ priors,
                                                 const float* __restrict__ targets,
                                                 unsigned long long* __restrict__ keys) {
    int b = blockIdx.y, tid = threadIdx.x;
    __shared__ float tr[OO][4];
    __shared__ unsigned long long skeys[OO];
    if (tid < OO * 5) {
        int o = tid / 5, c = tid % 5;
        float v = targets[((size_t)b * OO + o) * 5 + c];
        if (c < 4) tr[o][c] = v;
    }
    if (tid < OO) skeys[tid] = 0ull;
    __syncthreads();

    unsigned long long best[OO];
#pragma unroll
    for (int o = 0; o < OO; o++) best[o] = 0ull;

    for (int p = blockIdx.x * 256 + tid; p < PP; p += gridDim.x * 256) {
        float4 pr = ((const float4*)priors)[p];
        float bx0 = pr.x - pr.z * 0.5f, by0 = pr.y - pr.w * 0.5f;
        float bx1 = pr.x + pr.z * 0.5f, by1 = pr.y + pr.w * 0.5f;
        float area_b = (bx1 - bx0) * (by1 - by0);
#pragma unroll
        for (int o = 0; o < OO; o++) {
            float iw = fminf(tr[o][2], bx1) - fmaxf(tr[o][0], bx0);
            float ih = fminf(tr[o][3], by1) - fmaxf(tr[o][1], by0);
            iw = fmaxf(iw, 0.f); ih = fmaxf(ih, 0.f);
            float inter = iw * ih;
            float area_a = (tr[o][2] - tr[o][0]) * (tr[o][3] - tr[o][1]);
            float iou = inter / (area_a + area_b - inter);
            unsigned long long key =
                ((unsigned long long)__float_as_uint(iou) << 32) |
                (unsigned long long)(0xFFFFFFFFu - (unsigned)p);
            if (key > best[o]) best[o] = key;
        }
    }
#pragma unroll
    for (int o = 0; o < OO; o++) {
        unsigned long long v = best[o];
        for (int off = 32; off > 0; off >>= 1) {
            unsigned long long other = __shfl_down(v, off, 64);
            if (other > v) v = other;
        }
        best[o] = v;
    }
    if ((tid & 63) == 0) {
#pragma unroll
        for (int o = 0; o < OO; o++) atomicMax(&skeys[o], best[o]);
    }
    __syncthreads();
    if (tid < OO) atomicMax(&keys[b * OO + tid], skeys[tid]);
}

// ---------------- Phase C: match + encode + smooth-L1 + CE + mined ----------------
__device__ __forceinline__ float sl1(float d) {
    float a = fabsf(d);
    return (a < 1.f) ? 0.5f * d * d : a - 0.5f;
}

__global__ __launch_bounds__(256) void mb_phaseC(const float* __restrict__ loc_data,
                                                 const float* __restrict__ conf_data,
                                                 const float* __restrict__ priors,
                                                 const float* __restrict__ targets,
                                                 const unsigned long long* __restrict__ keys,
                                                 float* __restrict__ mined,
                                                 int* __restrict__ num_pos,
                                                 double* __restrict__ posCE,
                                                 double* __restrict__ loss_l_acc) {
    int b = blockIdx.y, tid = threadIdx.x;
    int wave = tid >> 6, lane = tid & 63;
    int p = blockIdx.x * 256 + tid;

    __shared__ float confs[4][64 * CC];   // 21504 B
    __shared__ float tr[OO][4];
    __shared__ float lab[OO];
    __shared__ unsigned bps[OO];
    __shared__ float redf[8];
    __shared__ int redi[4];

    if (tid < OO * 5) {
        int o = tid / 5, c = tid % 5;
        float v = targets[((size_t)b * OO + o) * 5 + c];
        if (c < 4) tr[o][c] = v; else lab[o] = v;
    }
    if (tid < OO) bps[tid] = 0xFFFFFFFFu - (unsigned)(keys[b * OO + tid] & 0xFFFFFFFFull);

    // stage this wave's 64 priors x 21 classes; float4 fast path when full tile
    int wbase = blockIdx.x * 256 + wave * 64;
    if (wbase < PP) {
        const float* src = conf_data + ((size_t)b * PP + wbase) * CC;
        float* dst = confs[wave];
        if (wbase + 64 <= PP) {
            // 1344 dwords = 336 float4, src 16B-aligned (offset multiple of 21*64 dwords)
            const float4* s4 = (const float4*)src;
            float4* d4 = (float4*)dst;
#pragma unroll
            for (int j = 0; j < 336; j += 64) {
                int idx = j + lane;
                if (idx < 336) d4[idx] = s4[idx];
            }
        } else {
            int ndw = (PP - wbase) * CC;
            for (int j = lane; j < ndw; j += 64) dst[j] = src[j];
        }
    }
    __syncthreads();

    float t_lossl = 0.f, t_posce = 0.f;
    int t_pos = 0;

    if (p < PP) {
        float4 pr = ((const float4*)priors)[p];
        float bx0 = pr.x - pr.z * 0.5f, by0 = pr.y - pr.w * 0.5f;
        float bx1 = pr.x + pr.z * 0.5f, by1 = pr.y + pr.w * 0.5f;
        float area_b = (bx1 - bx0) * (by1 - by0);
        float bto = -1.f;
        int bti = 0;
#pragma unroll
        for (int o = 0; o < OO; o++) {
            float iw = fminf(tr[o][2], bx1) - fmaxf(tr[o][0], bx0);
            float ih = fminf(tr[o][3], by1) - fmaxf(tr[o][1], by0);
            iw = fmaxf(iw, 0.f); ih = fmaxf(ih, 0.f);
            float inter = iw * ih;
            float area_a = (tr[o][2] - tr[o][0]) * (tr[o][3] - tr[o][1]);
            float iou = inter / (area_a + area_b - inter);
            if (iou > bto) { bto = iou; bti = o; }   // strict > : argmax first-index
        }
#pragma unroll
        for (int o = 0; o < OO; o++) {
            if (bps[o] == (unsigned)p) { bto = 2.0f; bti = o; }  // ascending o = last-wins
        }
        int conf_t = (bto < THRESHf) ? 0 : (int)lab[bti];
        bool pos = conf_t > 0;

        if (pos) {
            float mx0 = tr[bti][0], my0 = tr[bti][1], mx1 = tr[bti][2], my1 = tr[bti][3];
            float gcx = ((mx0 + mx1) * 0.5f - pr.x) / (VAR0f * pr.z);
            float gcy = ((my0 + my1) * 0.5f - pr.y) / (VAR0f * pr.w);
            float gw = logf((mx1 - mx0) / pr.z) / VAR1f;
            float gh = logf((my1 - my0) / pr.w) / VAR1f;
            float4 ld = ((const float4*)loc_data)[(size_t)b * PP + p];
            t_lossl = sl1(ld.x - gcx) + sl1(ld.y - gcy) + sl1(ld.z - gw) + sl1(ld.w - gh);
            t_pos = 1;
        }

        const float* cp = confs[wave] + lane * CC;   // stride-21 LDS: 2-way bank alias = free
        float m = cp[0];
#pragma unroll
        for (int c = 1; c < CC; c++) m = fmaxf(m, cp[c]);
        float s = 0.f;
#pragma unroll
        for (int c = 0; c < CC; c++) s += expf(cp[c] - m);
        float lse = m + logf(s);
        float ce = lse - cp[conf_t];
        if (pos) t_posce = ce;
        mined[(size_t)b * PP + p] = pos ? 0.f : ce;
    }

    // wave shuffle reductions
    for (int off = 32; off > 0; off >>= 1) {
        t_lossl += __shfl_down(t_lossl, off, 64);
        t_posce += __shfl_down(t_posce, off, 64);
        t_pos   += __shfl_down(t_pos, off, 64);
    }
    if (lane == 0) { redf[wave] = t_lossl; redf[4 + wave] = t_posce; redi[wave] = t_pos; }
    __syncthreads();
    if (tid == 0) {
        float ll = redf[0] + redf[1] + redf[2] + redf[3];
        float pc = redf[4] + redf[5] + redf[6] + redf[7];
        int np = redi[0] + redi[1] + redi[2] + redi[3];
        if (ll != 0.f) atomicAdd(loss_l_acc, (double)ll);
        if (pc != 0.f) atomicAdd(&posCE[b], (double)pc);
        if (np) atomicAdd(&num_pos[b], np);
    }
}

// ---------------- Phase D1: privatized LDS histogram, flushed once per nonzero bin ----------------
__global__ __launch_bounds__(256) void mb_phaseD1(const float* __restrict__ mined,
                                                  unsigned* __restrict__ hist) {
    int b = blockIdx.y, tid = threadIdx.x;
    __shared__ unsigned lh[HBINS];   // 32 KB
    for (int i = tid; i < HBINS; i += 256) lh[i] = 0;
    __syncthreads();
    const float* row = mined + (size_t)b * PP;
    for (int p = blockIdx.x * 256 + tid; p < PP; p += gridDim.x * 256)
        atomicAdd(&lh[__float_as_uint(row[p]) >> HSHIFT], 1u);
    __syncthreads();
    unsigned* gh = hist + (size_t)b * HBINS;
    for (int i = tid; i < HBINS; i += 256) {
        unsigned c = lh[i];
        if (c) atomicAdd(&gh[i], c);
    }
}

// ---------------- Phase D2: histogram-select top-num_neg + exact in-bin rank-select ----------------
__global__ __launch_bounds__(256) void mb_phaseD2(const float* __restrict__ mined,
                                                  const unsigned* __restrict__ hist,
                                                  const int* __restrict__ num_pos,
                                                  const double* __restrict__ posCE,
                                                  double* __restrict__ loss_c_acc) {
    int b = blockIdx.x, tid = threadIdx.x;
    int np = num_pos[b];
    int k = min(3 * np, PP - 1);
    if (k <= 0) {
        if (tid == 0) atomicAdd(loss_c_acc, posCE[b]);
        return;
    }
    const float* row = mined + (size_t)b * PP;
    const unsigned* h = hist + (size_t)b * HBINS;
    const int CH = HBINS / 256;   // 32 bins per thread

    __shared__ unsigned cs[256];
    __shared__ int sBin;
    __shared__ unsigned sAbove;
    __shared__ double sd[256];

    unsigned s = 0;
    for (int j = 0; j < CH; j++) s += h[tid * CH + j];
    cs[tid] = s;
    __syncthreads();
    if (tid == 0) {
        unsigned cum = 0;
        int t = 255;
        for (; t > 0; --t) {
            if (cum + cs[t] >= (unsigned)k) break;
            cum += cs[t];
        }
        int base = t * CH, bin = base;
        unsigned cum2 = cum;
        for (int j = CH - 1; j >= 1; --j) {
            unsigned c = h[base + j];
            if (cum2 + c >= (unsigned)k) { bin = base + j; break; }
            cum2 += c;
        }
        sBin = bin;
        sAbove = cum2;
    }
    __syncthreads();
    int bin = sBin;
    int need = k - (int)sAbove;        // 1..h[bin]
    unsigned binCount = h[bin];

    if (binCount <= CAND_MAX) {
        __shared__ float cand[CAND_MAX];
        __shared__ unsigned ccnt;
        if (tid == 0) ccnt = 0;
        __syncthreads();
        double sgt = 0.0;
        for (int p = tid; p < PP; p += 256) {
            float x = row[p];
            int bb = (int)(__float_as_uint(x) >> HSHIFT);
            if (bb > bin) sgt += (double)x;
            else if (bb == bin) { unsigned i = atomicAdd(&ccnt, 1u); cand[i] = x; }
        }
        sd[tid] = sgt;
        __syncthreads();
        for (int s2 = 128; s2 > 0; s2 >>= 1) {
            if (tid < s2) sd[tid] += sd[tid + s2];
            __syncthreads();
        }
        double sum_gt = sd[0];
        int n = (int)ccnt;
        __syncthreads();
        // exact rank-select: include candidate i iff stable-rank < need (ties sum identically)
        double st = 0.0;
        for (int i = tid; i < n; i += 256) {
            float v = cand[i];
            int r = 0;
            for (int j = 0; j < n; j++) {
                float w = cand[j];
                r += (w > v) || (w == v && j < i);
            }
            if (r < need) st += (double)v;
        }
        sd[tid] = st;
        __syncthreads();
        for (int s2 = 128; s2 > 0; s2 >>= 1) {
            if (tid < s2) sd[tid] += sd[tid + s2];
            __syncthreads();
        }
        if (tid == 0) atomicAdd(loss_c_acc, posCE[b] + sum_gt + sd[0]);
    } else {
        // fallback: known-correct 4-pass byte radix select over full 32 bits
        __shared__ unsigned rhist[256];
        __shared__ unsigned s_prefix;
        __shared__ int s_needed;
        unsigned prefix = 0;
        int needed = k;
        for (int pass = 0; pass < 4; pass++) {
            int shift = 24 - 8 * pass;
            for (int i = tid; i < 256; i += 256) rhist[i] = 0;
            __syncthreads();
            unsigned hi_mask = (pass == 0) ? 0u : (0xFFFFFFFFu << (shift + 8));
            for (int p = tid; p < PP; p += 256) {
                unsigned x = __float_as_uint(row[p]);
                if ((x & hi_mask) == (prefix & hi_mask))
                    atomicAdd(&rhist[(x >> shift) & 0xFFu], 1u);
            }
            __syncthreads();
            if (tid == 0) {
                unsigned cum = 0; int bsel = 0;
                for (int j = 255; j >= 0; j--) {
                    if (cum + rhist[j] >= (unsigned)needed) { bsel = j; break; }
                    cum += rhist[j];
                }
                s_prefix = prefix | ((unsigned)bsel << shift);
                s_needed = needed - (int)cum;
            }
            __syncthreads();
            prefix = s_prefix;
            needed = s_needed;
            __syncthreads();
        }
        float t = __uint_as_float(prefix);
        double sum_gt = 0.0;
        for (int p = tid; p < PP; p += 256) {
            float x = row[p];
            if (__float_as_uint(x) > prefix) sum_gt += (double)x;
        }
        sd[tid] = sum_gt;
        __syncthreads();
        for (int s2 = 128; s2 > 0; s2 >>= 1) {
            if (tid < s2) sd[tid] += sd[tid + s2];
            __syncthreads();
        }
        if (tid == 0)
            atomicAdd(loss_c_acc, posCE[b] + sd[0] + (double)needed * (double)t);
    }
}

// ---------------- Phase E: finalize ----------------
__global__ __launch_bounds__(128) void mb_phaseE(const int* __restrict__ num_pos,
                                                 const double* __restrict__ loss_l_acc,
                                                 const double* __restrict__ loss_c_acc,
                                                 float* __restrict__ out) {
    __shared__ int si[128];
    int tid = threadIdx.x;
    si[tid] = (tid < BB) ? num_pos[tid] : 0;
    __syncthreads();
    for (int s = 64; s > 0; s >>= 1) {
        if (tid < s) si[tid] += si[tid + s];
        __syncthreads();
    }
    if (tid == 0) {
        int n = si[0];
        double N = (n > 0) ? (double)n : (double)BB;
        out[0] = (float)(*loss_l_acc / N);
        out[1] = (float)(*loss_c_acc / N);
    }
}

extern "C" void kernel_launch(void* const* d_in, const int* in_sizes, int n_in,
                              void* d_out, int out_size, void* d_ws, size_t ws_size,
                              hipStream_t stream) {
    const float* loc_data  = (const float*)d_in[0];
    const float* conf_data = (const float*)d_in[1];
    const float* priors    = (const float*)d_in[2];
    const float* targets   = (const float*)d_in[3];

    char* ws = (char*)d_ws;
    // layout: [0..8) loss_l, [8..16) loss_c, [64..576) num_pos[B],
    //         [1024..2048) posCE[B], [2048..18432) keys[B*16] u64,
    //         [32768..32768+4MB) hist[B*8192] u32, then mined[B*P] f32
    double*             loss_l  = (double*)(ws + 0);
    double*             loss_c  = (double*)(ws + 8);
    int*                num_pos = (int*)(ws + 64);
    double*             posCE   = (double*)(ws + 1024);
    unsigned long long* keys    = (unsigned long long*)(ws + 2048);
    unsigned*           hist    = (unsigned*)(ws + 32768);
    float*              mined   = (float*)(ws + 32768 + (size_t)BB * HBINS * 4);

    hipMemsetAsync(ws, 0, 32768 + (size_t)BB * HBINS * 4, stream);

    mb_phaseA<<<dim3(8, BB), 256, 0, stream>>>(priors, targets, keys);

    dim3 gridC((PP + 255) / 256, BB);
    mb_phaseC<<<gridC, 256, 0, stream>>>(loc_data, conf_data, priors, targets, keys,
                                         mined, num_pos, posCE, loss_l);

    mb_phaseD1<<<dim3(8, BB), 256, 0, stream>>>(mined, hist);

    mb_phaseD2<<<BB, 256, 0, stream>>>(mined, hist, num_pos, posCE, loss_c);

    mb_phaseE<<<1, 128, 0, stream>>>(num_pos, loss_l, loss_c, (float*)d_out);
}